// Round 2
// baseline (736.431 us; speedup 1.0000x reference)
//
#include <hip/hip_runtime.h>

#define EPS 1e-4f
#define BB 64
#define NN 1024   // N1 == N2 == 1024 (static per reference)

// ---------------------------------------------------------------------------
// c_j = 1 / sum_{i<nr} (s[b,i,j]+EPS) * r_i     (r == 1 when first)
// Stage 1: partial sums over 128-row chunks. grid (8, B), block 256.
// Thread t owns columns [4t, 4t+4) via float4; loads are coalesced (wave
// reads 1 KiB contiguous per row). Columns >= nc skip loads entirely.
// ---------------------------------------------------------------------------
__global__ __launch_bounds__(256) void colsum_partial_k(
    const float* __restrict__ s, const float* __restrict__ r,
    const int* __restrict__ nrows, const int* __restrict__ ncols,
    float* __restrict__ partial, int first)
{
    int chunk = blockIdx.x;          // 0..7
    int b     = blockIdx.y;
    int nr = nrows[b], nc = ncols[b];
    int t = threadIdx.x;
    int j = t << 2;
    float4 acc = make_float4(0.f, 0.f, 0.f, 0.f);
    int i0 = chunk << 7;
    int i1 = min(i0 + 128, nr);
    if (j < nc) {
        const float* sb = s + ((size_t)b << 20) + j;
        const float* rb = r + (b << 10);
        for (int i = i0; i < i1; ++i) {
            float4 v = *(const float4*)(sb + ((size_t)i << 10));
            float ri = first ? 1.0f : rb[i];   // wave-uniform -> scalar load
            acc.x += (v.x + EPS) * ri;
            acc.y += (v.y + EPS) * ri;
            acc.z += (v.z + EPS) * ri;
            acc.w += (v.w + EPS) * ri;
        }
    }
    *(float4*)(partial + (((size_t)(b * 8 + chunk)) << 10) + j) = acc;
}

// Stage 2: reduce 8 chunk partials, reciprocal. grid (4, B), block 256.
// c beyond nc may be 1/0 = inf -- all consumers select-mask it, never multiply.
__global__ __launch_bounds__(256) void colsum_reduce_k(
    const float* __restrict__ partial, float* __restrict__ c)
{
    int b = blockIdx.y;
    int j = (blockIdx.x << 8) + threadIdx.x;
    const float* pb = partial + (((size_t)(b * 8)) << 10) + j;
    float u = 0.f;
#pragma unroll
    for (int k = 0; k < 8; ++k) u += pb[(size_t)k << 10];
    c[(b << 10) + j] = 1.0f / u;
}

// ---------------------------------------------------------------------------
// r_i = 1 / sum_{j<nc} (s[b,i,j]+EPS) * c_j
// grid (256, B), block 256 = 4 waves; wave w owns row blockIdx.x*4 + w.
// c is staged into LDS pre-masked (0 beyond nc) so the float4 boundary at a
// non-multiple-of-4 nc is handled by multiply-by-zero (c is finite there
// after masking, so no NaN). Rows >= nr exit after the staging barrier.
// ---------------------------------------------------------------------------
__global__ __launch_bounds__(256) void rowsum_k(
    const float* __restrict__ s, const float* __restrict__ c,
    const int* __restrict__ nrows, const int* __restrict__ ncols,
    float* __restrict__ r)
{
    __shared__ float cs[NN];
    int b = blockIdx.y;
    int nr = nrows[b], nc = ncols[b];
    int t = threadIdx.x;
    {
        int j = t << 2;
        float4 cv = *(const float4*)(c + (b << 10) + j);
        cs[j + 0] = (j + 0 < nc) ? cv.x : 0.f;
        cs[j + 1] = (j + 1 < nc) ? cv.y : 0.f;
        cs[j + 2] = (j + 2 < nc) ? cv.z : 0.f;
        cs[j + 3] = (j + 3 < nc) ? cv.w : 0.f;
    }
    __syncthreads();
    int w = t >> 6, lane = t & 63;
    int i = (blockIdx.x << 2) + w;
    if (i >= nr) return;
    const float* srow = s + ((size_t)b << 20) + ((size_t)i << 10);
    float4 acc = make_float4(0.f, 0.f, 0.f, 0.f);
#pragma unroll
    for (int k = 0; k < 4; ++k) {
        int j = (k << 8) + (lane << 2);
        if (j < nc) {   // skip whole-float4 loads beyond nc (saves BW)
            float4 v  = *(const float4*)(srow + j);
            float4 cv = *(const float4*)(&cs[j]);
            acc.x += (v.x + EPS) * cv.x;
            acc.y += (v.y + EPS) * cv.y;
            acc.z += (v.z + EPS) * cv.z;
            acc.w += (v.w + EPS) * cv.w;
        }
    }
    float sum = (acc.x + acc.y) + (acc.z + acc.w);
#pragma unroll
    for (int o = 32; o > 0; o >>= 1) sum += __shfl_xor(sum, o, 64);
    if (lane == 0) r[(b << 10) + i] = 1.0f / sum;
}

// ---------------------------------------------------------------------------
// Fused 5th row-normalization + finalize. grid (1024, B), block 256.
// One block per row; thread t holds the row's float4 at j=4t in registers,
// computes p = (s+EPS)*c (masked), block-reduces sum(p) -> r_i = 1/sum,
// stores p*r_i. Saves a full read pass over the valid region vs a separate
// rowsum + finalize.
// ---------------------------------------------------------------------------
__global__ __launch_bounds__(256) void finalize_fused_k(
    const float* __restrict__ s, const float* __restrict__ c,
    const int* __restrict__ nrows, const int* __restrict__ ncols,
    float* __restrict__ out)
{
    __shared__ float red[4];
    int b = blockIdx.y, i = blockIdx.x;
    int nr = nrows[b], nc = ncols[b];
    int t = threadIdx.x;
    int j = t << 2;
    size_t off = ((size_t)b << 20) + ((size_t)i << 10) + j;

    if (i >= nr) {   // whole-block-uniform: all threads take this path together
        *(float4*)(out + off) = make_float4(0.f, 0.f, 0.f, 0.f);
        return;
    }

    float4 p = make_float4(0.f, 0.f, 0.f, 0.f);
    if (j < nc) {
        float4 cv = *(const float4*)(c + (b << 10) + j);
        float4 v  = *(const float4*)(s + off);
        float c0 = (j + 0 < nc) ? cv.x : 0.f;   // select, never multiply inf
        float c1 = (j + 1 < nc) ? cv.y : 0.f;
        float c2 = (j + 2 < nc) ? cv.z : 0.f;
        float c3 = (j + 3 < nc) ? cv.w : 0.f;
        p.x = (v.x + EPS) * c0;
        p.y = (v.y + EPS) * c1;
        p.z = (v.z + EPS) * c2;
        p.w = (v.w + EPS) * c3;
    }
    float sum = (p.x + p.y) + (p.z + p.w);
#pragma unroll
    for (int o = 32; o > 0; o >>= 1) sum += __shfl_xor(sum, o, 64);
    int w = t >> 6, lane = t & 63;
    if (lane == 0) red[w] = sum;
    __syncthreads();
    float total = (red[0] + red[1]) + (red[2] + red[3]);
    float ri = 1.0f / total;
    float4 o = make_float4(p.x * ri, p.y * ri, p.z * ri, p.w * ri);
    *(float4*)(out + off) = o;
}

extern "C" void kernel_launch(void* const* d_in, const int* in_sizes, int n_in,
                              void* d_out, int out_size, void* d_ws, size_t ws_size,
                              hipStream_t stream) {
    const float* s     = (const float*)d_in[0];
    // d_in[1] = n1, d_in[2] = n2 (static 1024, unused)
    const int*   nrows = (const int*)d_in[3];
    const int*   ncols = (const int*)d_in[4];
    float* out = (float*)d_out;

    float* r       = (float*)d_ws;              // B*1024 floats
    float* c       = r + BB * NN;               // B*1024 floats
    float* partial = c + BB * NN;               // B*8*1024 floats (2 MiB)

    // 10 Sinkhorn iterations == 5 pairs of (col-normalize, row-normalize),
    // expressed as scale-vector updates: c = 1/(A^T r), r = 1/(A c).
    // Prior-iteration scale factors cancel algebraically, so only the
    // current r (resp. c) enters each update. The 5th row-normalization is
    // fused into finalize.
    for (int it = 0; it < 5; ++it) {
        colsum_partial_k<<<dim3(8, BB), 256, 0, stream>>>(s, r, nrows, ncols,
                                                          partial, it == 0);
        colsum_reduce_k<<<dim3(4, BB), 256, 0, stream>>>(partial, c);
        if (it < 4)
            rowsum_k<<<dim3(NN / 4, BB), 256, 0, stream>>>(s, c, nrows, ncols, r);
    }
    finalize_fused_k<<<dim3(NN, BB), 256, 0, stream>>>(s, c, nrows, ncols, out);
}

// Round 3
// 569.699 us; speedup vs baseline: 1.2927x; 1.2927x over previous
//
#include <hip/hip_runtime.h>

#define EPS 1e-4f
#define BB 64
#define NN 1024   // N1 == N2 == 1024 (static per reference)

typedef _Float16 f16x8 __attribute__((ext_vector_type(8)));
typedef _Float16 f16x4 __attribute__((ext_vector_type(4)));

// ---------------------------------------------------------------------------
// K1: compress s -> A (fp16, +EPS, zero-padded beyond nc) and first column
// sums (r == 1). grid (16, B) -- 16 chunks x 64 rows; block 256.
// Thread t owns cols [4t, 4t+4). Rows >= nr are skipped (A garbage there is
// never read). partial layout: [chunk][b][1024].
// ---------------------------------------------------------------------------
__global__ __launch_bounds__(256) void compress_colsum_k(
    const float* __restrict__ s, _Float16* __restrict__ A,
    const int* __restrict__ nrows, const int* __restrict__ ncols,
    float* __restrict__ partial)
{
    int chunk = blockIdx.x;
    int b = blockIdx.y;
    int nr = nrows[b], nc = ncols[b];
    int t = threadIdx.x;
    int j = t << 2;
    int i0 = chunk << 6;
    int i1 = min(i0 + 64, nr);
    const float* sb = s + ((size_t)b << 20) + j;
    _Float16* Ab = A + ((size_t)b << 20) + j;
    float a0 = 0.f, a1 = 0.f, a2 = 0.f, a3 = 0.f;
    if (j < nc) {
        for (int i = i0; i < i1; ++i) {
            float4 v = *(const float4*)(sb + ((size_t)i << 10));
            float m0 = (j + 0 < nc) ? v.x + EPS : 0.f;
            float m1 = (j + 1 < nc) ? v.y + EPS : 0.f;
            float m2 = (j + 2 < nc) ? v.z + EPS : 0.f;
            float m3 = (j + 3 < nc) ? v.w + EPS : 0.f;
            f16x4 h;
            h[0] = (_Float16)m0; h[1] = (_Float16)m1;
            h[2] = (_Float16)m2; h[3] = (_Float16)m3;
            // accumulate the ROUNDED values so c1 is exactly consistent with A
            a0 += (float)h[0]; a1 += (float)h[1];
            a2 += (float)h[2]; a3 += (float)h[3];
            *(f16x4*)(Ab + ((size_t)i << 10)) = h;
        }
    } else {
        f16x4 z = {};
        for (int i = i0; i < i1; ++i)
            *(f16x4*)(Ab + ((size_t)i << 10)) = z;
    }
    *(float4*)(partial + (((size_t)((chunk << 6) + b)) << 10) + j) =
        make_float4(a0, a1, a2, a3);
}

// ---------------------------------------------------------------------------
// K2: fused (row-normalize -> next column-sum). grid (16, B), block 256.
// Stage c = 1/colsum (masked) into LDS from 16-chunk partials; each wave owns
// rows chunk*64 + w, +4: holds the full 1024-wide fp16 row in regs (16/lane),
// computes r_i = 1/sum(A*c) via 64-lane butterfly, then accumulates A*r_i
// into per-wave column accumulators; block merges 4 waves via LDS -> pout.
// r never touches global memory. A is read exactly once per iteration.
// ---------------------------------------------------------------------------
__global__ __launch_bounds__(256) void pair_k(
    const _Float16* __restrict__ A, const float* __restrict__ pin,
    const int* __restrict__ nrows, const int* __restrict__ ncols,
    float* __restrict__ pout)
{
    __shared__ float cs[NN];        // 4 KB
    __shared__ float mg[4][NN];     // 16 KB
    int chunk = blockIdx.x, b = blockIdx.y;
    int nr = nrows[b], nc = ncols[b];
    int t = threadIdx.x;
    {
        int j = t << 2;
        const float* pb = pin + ((size_t)b << 10) + j;
        float4 u = make_float4(0.f, 0.f, 0.f, 0.f);
#pragma unroll
        for (int k = 0; k < 16; ++k) {          // chunk stride = 64*1024 = 1<<16
            float4 p = *(const float4*)(pb + ((size_t)k << 16));
            u.x += p.x; u.y += p.y; u.z += p.z; u.w += p.w;
        }
        cs[j + 0] = (j + 0 < nc) ? 1.0f / u.x : 0.f;
        cs[j + 1] = (j + 1 < nc) ? 1.0f / u.y : 0.f;
        cs[j + 2] = (j + 2 < nc) ? 1.0f / u.z : 0.f;
        cs[j + 3] = (j + 3 < nc) ? 1.0f / u.w : 0.f;
    }
    __syncthreads();

    int w = t >> 6, lane = t & 63;
    int col0 = lane << 3;                 // step0 cols [col0, col0+8)
    float4 c0a = *(const float4*)&cs[col0];
    float4 c0b = *(const float4*)&cs[col0 + 4];
    float4 c1a = *(const float4*)&cs[512 + col0];
    float4 c1b = *(const float4*)&cs[512 + col0 + 4];
    bool do1 = (512 + col0) < nc;         // nc >= 512 so step0 is always live

    float acc0[8] = {0.f, 0.f, 0.f, 0.f, 0.f, 0.f, 0.f, 0.f};
    float acc1[8] = {0.f, 0.f, 0.f, 0.f, 0.f, 0.f, 0.f, 0.f};
    const _Float16* Ab = A + ((size_t)b << 20);
    int i0 = chunk << 6;
    int iend = min(i0 + 64, nr);
    for (int i = i0 + w; i < iend; i += 4) {
        const _Float16* row = Ab + ((size_t)i << 10);
        f16x8 q0 = *(const f16x8*)(row + col0);
        f16x8 q1 = {};
        if (do1) q1 = *(const f16x8*)(row + 512 + col0);
        float f0[8], f1[8];
#pragma unroll
        for (int k = 0; k < 8; ++k) { f0[k] = (float)q0[k]; f1[k] = (float)q1[k]; }
        float sum = f0[0]*c0a.x + f0[1]*c0a.y + f0[2]*c0a.z + f0[3]*c0a.w
                  + f0[4]*c0b.x + f0[5]*c0b.y + f0[6]*c0b.z + f0[7]*c0b.w
                  + f1[0]*c1a.x + f1[1]*c1a.y + f1[2]*c1a.z + f1[3]*c1a.w
                  + f1[4]*c1b.x + f1[5]*c1b.y + f1[6]*c1b.z + f1[7]*c1b.w;
#pragma unroll
        for (int o = 32; o > 0; o >>= 1) sum += __shfl_xor(sum, o, 64);
        float ri = 1.0f / sum;            // all lanes have the full row sum
#pragma unroll
        for (int k = 0; k < 8; ++k) { acc0[k] += f0[k] * ri; acc1[k] += f1[k] * ri; }
    }
    *(float4*)&mg[w][col0]       = make_float4(acc0[0], acc0[1], acc0[2], acc0[3]);
    *(float4*)&mg[w][col0 + 4]   = make_float4(acc0[4], acc0[5], acc0[6], acc0[7]);
    *(float4*)&mg[w][512 + col0]     = make_float4(acc1[0], acc1[1], acc1[2], acc1[3]);
    *(float4*)&mg[w][512 + col0 + 4] = make_float4(acc1[4], acc1[5], acc1[6], acc1[7]);
    __syncthreads();
    int j = t << 2;
    float4 m = make_float4(0.f, 0.f, 0.f, 0.f);
#pragma unroll
    for (int ww = 0; ww < 4; ++ww) {
        float4 v = *(const float4*)&mg[ww][j];
        m.x += v.x; m.y += v.y; m.z += v.z; m.w += v.w;
    }
    *(float4*)(pout + (((size_t)((chunk << 6) + b)) << 10) + j) = m;
}

// ---------------------------------------------------------------------------
// K3: reduce 16-chunk partials -> c (masked reciprocal). grid (4, B).
// ---------------------------------------------------------------------------
__global__ __launch_bounds__(256) void reduce_c_k(
    const float* __restrict__ partial, const int* __restrict__ ncols,
    float* __restrict__ c)
{
    int b = blockIdx.y;
    int j = (blockIdx.x << 8) + threadIdx.x;
    int nc = ncols[b];
    const float* pb = partial + ((size_t)b << 10) + j;
    float u = 0.f;
#pragma unroll
    for (int k = 0; k < 16; ++k) u += pb[(size_t)k << 16];
    c[(b << 10) + j] = (j < nc) ? 1.0f / u : 0.f;
}

// ---------------------------------------------------------------------------
// K4: fused 5th row-normalize + finalize, reading fp16 A. grid (1024, B),
// one block per row. p = A*c (both pre-masked/padded -> 0 beyond nc, no inf
// anywhere); block-reduce sum(p) -> r_i = 1/sum; store p*r_i. Rows >= nr
// write zeros without loading.
// ---------------------------------------------------------------------------
__global__ __launch_bounds__(256) void finalize_k(
    const _Float16* __restrict__ A, const float* __restrict__ c,
    const int* __restrict__ nrows, float* __restrict__ out)
{
    __shared__ float red[4];
    int b = blockIdx.y, i = blockIdx.x;
    int nr = nrows[b];
    int t = threadIdx.x;
    int j = t << 2;
    size_t off = ((size_t)b << 20) + ((size_t)i << 10) + j;
    if (i >= nr) {   // block-uniform branch
        *(float4*)(out + off) = make_float4(0.f, 0.f, 0.f, 0.f);
        return;
    }
    f16x4 h = *(const f16x4*)(A + off);
    float4 cv = *(const float4*)(c + (b << 10) + j);
    float4 p;
    p.x = (float)h[0] * cv.x;
    p.y = (float)h[1] * cv.y;
    p.z = (float)h[2] * cv.z;
    p.w = (float)h[3] * cv.w;
    float sum = (p.x + p.y) + (p.z + p.w);
#pragma unroll
    for (int o = 32; o > 0; o >>= 1) sum += __shfl_xor(sum, o, 64);
    int w = t >> 6, lane = t & 63;
    if (lane == 0) red[w] = sum;
    __syncthreads();
    float total = (red[0] + red[1]) + (red[2] + red[3]);
    float ri = 1.0f / total;
    *(float4*)(out + off) = make_float4(p.x * ri, p.y * ri, p.z * ri, p.w * ri);
}

extern "C" void kernel_launch(void* const* d_in, const int* in_sizes, int n_in,
                              void* d_out, int out_size, void* d_ws, size_t ws_size,
                              hipStream_t stream) {
    const float* s     = (const float*)d_in[0];
    // d_in[1] = n1, d_in[2] = n2 (static 1024, unused)
    const int*   nrows = (const int*)d_in[3];
    const int*   ncols = (const int*)d_in[4];
    float* out = (float*)d_out;

    // ws layout: A (fp16, 134.2 MB) | partialA (4 MB) | partialB (4 MB) | c (256 KB)
    _Float16* A  = (_Float16*)d_ws;
    float* pA    = (float*)((char*)d_ws + ((size_t)BB << 20) * sizeof(_Float16));
    float* pB    = pA + ((size_t)16 * BB * NN);
    float* c5    = pB + ((size_t)16 * BB * NN);

    // 10 Sinkhorn iterations = 5 col-normalizes (c1..c5) + 5 row-normalizes
    // (r1..r5), as scale-vector updates. r1..r4 live only inside pair_k; r5
    // is fused into finalize.
    compress_colsum_k<<<dim3(16, BB), 256, 0, stream>>>(s, A, nrows, ncols, pA);
    pair_k<<<dim3(16, BB), 256, 0, stream>>>(A, pA, nrows, ncols, pB); // c1 -> c2 partial
    pair_k<<<dim3(16, BB), 256, 0, stream>>>(A, pB, nrows, ncols, pA); // c2 -> c3
    pair_k<<<dim3(16, BB), 256, 0, stream>>>(A, pA, nrows, ncols, pB); // c3 -> c4
    pair_k<<<dim3(16, BB), 256, 0, stream>>>(A, pB, nrows, ncols, pA); // c4 -> c5
    reduce_c_k<<<dim3(4, BB), 256, 0, stream>>>(pA, ncols, c5);
    finalize_k<<<dim3(NN, BB), 256, 0, stream>>>(A, c5, nrows, out);
}